// Round 12
// baseline (194.538 us; speedup 1.0000x reference)
//
#include <hip/hip_runtime.h>
#include <stdint.h>

// SpatialHyperedgeMP: out = ((inc + head) @ cur) / rowsum(inc + head)
//   head_ij = (inc_ij > 0) / sqrt(cnt_i),  cnt_i = #positives in row i
// Decomposition (single fused pass over inc):
//   out[i] = (inc@cur + invs_i * (mask@cur)) * rdeg_i
//   invs_i = 1/sqrt(cnt_i),  rdeg_i = 1/(s1_i + sqrt(cnt_i))
//
// R12 = R11 with the mask operand M moved from LDS to in-register derivation.
//   R11 post-mortem: DS pipe was the top consumer (~64%) because all 8 waves
//   re-read identical A AND M frags (64 b128/block/tile). M is derivable from
//   the A bf16 frag in 6 VALU ops/dword (R5-verified pos-mask bit trick), and
//   VALU sat at only 24%. So: M frag = f(A frag) in regs; M LDS buffer, M
//   ds_writes, M ds_reads all deleted. DS ~1920 -> ~900 cyc/tile-pair.
//   Everything else identical to R11 (best: 167 us).
//
// ws usage: 8MB B chunks only.

#define NROWS 8192
#define DDIM  512

typedef float f32x4 __attribute__((ext_vector_type(4)));
typedef short s16x8 __attribute__((ext_vector_type(8)));
typedef unsigned int u32x4 __attribute__((ext_vector_type(4)));

__device__ __forceinline__ unsigned short f2bf(float f) {
  union { float f; unsigned int u; } c; c.f = f;
  unsigned int u = c.u;
  unsigned int r = u + 0x7FFFu + ((u >> 16) & 1u);
  return (unsigned short)(r >> 16);
}

// bf16-pair positive test: per 16-bit half, 0x3F80 (bf16 1.0) if value > 0 else 0.
// (R5-verified: halfwise mag!=0 AND sign==0; probability of fp32>0 rounding to
// bf16 +0 is the subnormal range ~2^-133 — negligible for N(0,1) data, and only
// affects the numerator by ~invs*cur on that element.)
__device__ __forceinline__ s16x8 pos_mask_frag(s16x8 a) {
  union { s16x8 s; u32x4 u; } in, out;
  in.s = a;
#pragma unroll
  for (int i = 0; i < 4; ++i) {
    unsigned int v = in.u[i];
    unsigned int nz = ((v & 0x7FFF7FFFu) + 0x7FFF7FFFu) & 0x80008000u;  // mag != 0
    unsigned int pos = nz & ~v;                                          // and sign==0
    out.u[i] = (pos >> 15) * 0x3F80u;  // bit0/bit16 -> 0x3F80 per half (u24 mul)
  }
  return out.s;
}

// ---------------- kernel 1: B prep (cur -> bf16 chunked-transposed) ----------------
// chunk layout: nt(2) x kt(128): 32KB chunk = [kg=8][nn=256][e=8] bf16
__global__ __launch_bounds__(256) void bprep_kernel(const float* __restrict__ cur,
                                                    unsigned char* __restrict__ bws) {
  int idx = blockIdx.x * 256 + threadIdx.x;  // 0..524287
  int n = idx & 511;
  int kg9 = idx >> 9;  // 0..1023
  int kt = kg9 >> 3;
  int kg = kg9 & 7;
  int k0 = kt * 64 + kg * 8;
  union { unsigned short h[8]; uint4 q; } u;
#pragma unroll
  for (int e = 0; e < 8; ++e)
    u.h[e] = f2bf(cur[(size_t)(k0 + e) * DDIM + n]);
  int nt = n >> 8, nn = n & 255;
  size_t off = ((size_t)(nt * 128 + kt) << 15) + ((size_t)kg << 12) + ((size_t)nn << 4);
  *(uint4*)(bws + off) = u.q;
}

// ---------------- kernel 2: fused stats + dual-GEMM ----------------
// BM=32 BN=256 BK=64, 512 thr = 8 waves (1M x 8N), wave tile 32x32.
// LDS (8.3KB): A bf16 dbuf 2x4KB ([kg=8][slot=32][16B], slot=row^kg, 0-conflict);
// stats reuse buf0 after the K-loop.

#define FENCE() __builtin_amdgcn_sched_barrier(0)
#define BARRIER() __builtin_amdgcn_s_barrier()
#define WAITLGKM() asm volatile("s_waitcnt lgkmcnt(0)" ::: "memory")
#define MFMA_ __builtin_amdgcn_mfma_f32_16x16x32_bf16

__global__ __launch_bounds__(512, 4) void gemm_kernel(const float* __restrict__ inc,
                                                      const unsigned char* __restrict__ bws,
                                                      float* __restrict__ out) {
  __shared__ __align__(16) unsigned char smem[8448];
  unsigned char* const buf0 = smem;
  unsigned char* const buf1 = smem + 4096;

  const int tid = threadIdx.x;
  const int lane = tid & 63;
  const int wv = tid >> 6;       // 0..7 column group
  const int r = lane & 15;
  const int q = lane >> 4;       // 0..3

  const int id = blockIdx.x;     // 0..511
  const int nt = (id & 7) >> 2;  // XCD half -> fixed 4MB B chunk per XCD L2
  const int mt = (id >> 3) * 4 + (id & 3);   // 0..255; partners id,id^4 adjacent
  const int brow = mt * 32;

  // ---- A staging ownership: thread -> (row sm, float4-slot sp) ----
  const int sm = tid >> 4;       // 0..31
  const int sp = tid & 15;       // 0..15 (k = sp*4..sp*4+3)
  const int kgw = sp >> 1, half = sp & 1;
  const float4* gAr = (const float4*)(inc + (size_t)(brow + sm) * NROWS) + sp;
  const int aWr = (kgw << 9) + ((sm ^ kgw) << 4) + (half << 3);

  // ---- A frag LDS offsets: frag(kh,rg): kg=kh*4+q, row=rg*16+r ----
  int aOff[2][2];
#pragma unroll
  for (int kh = 0; kh < 2; ++kh)
#pragma unroll
    for (int rg = 0; rg < 2; ++rg) {
      int kg = kh * 4 + q;
      int row = rg * 16 + r;
      aOff[kh][rg] = (kg << 9) + ((row ^ kg) << 4);
    }

  // ---- B frag ws offsets (within 32KB kt-chunk) ----
  const unsigned char* gB = bws + ((size_t)(nt * 128) << 15);
  int bOff[4];  // [kh*2+cg]
#pragma unroll
  for (int kh = 0; kh < 2; ++kh)
#pragma unroll
    for (int cg = 0; cg < 2; ++cg)
      bOff[kh * 2 + cg] = ((kh * 4 + q) << 12) + ((wv * 32 + cg * 16 + r) << 4);

  f32x4 acc1[2][2], acc2[2][2];
#pragma unroll
  for (int a = 0; a < 2; ++a)
#pragma unroll
    for (int b = 0; b < 2; ++b) {
      acc1[a][b] = (f32x4){0.f, 0.f, 0.f, 0.f};
      acc2[a][b] = (f32x4){0.f, 0.f, 0.f, 0.f};
    }

  double s1 = 0.0;
  int cnt = 0;
  float4 x, y;
  s16x8 bX[4], bY[4];

#define ISSUE_A(d, KT) do { d = gAr[(KT) * 16]; } while (0)

#define LOADB(BS, KT) do {                                                                \
    const unsigned char* _g = gB + ((size_t)(KT) << 15);                                  \
    BS[0] = *(const s16x8*)(_g + bOff[0]);                                                \
    BS[1] = *(const s16x8*)(_g + bOff[1]);                                                \
    BS[2] = *(const s16x8*)(_g + bOff[2]);                                                \
    BS[3] = *(const s16x8*)(_g + bOff[3]);                                                \
  } while (0)

// stage one float4: exact stats + bf16 A -> LDS (single b64)
#define XFORM(v, BUF) do {                                                                \
    s1 += (double)v.x + (double)v.y + (double)v.z + (double)v.w;                          \
    cnt += (v.x > 0.f) + (v.y > 0.f) + (v.z > 0.f) + (v.w > 0.f);                         \
    unsigned dlo, dhi;                                                                    \
    asm("v_cvt_pk_bf16_f32 %0, %1, %2" : "=v"(dlo) : "v"(v.x), "v"(v.y));                 \
    asm("v_cvt_pk_bf16_f32 %0, %1, %2" : "=v"(dhi) : "v"(v.z), "v"(v.w));                 \
    *(unsigned long long*)((BUF) + aWr) =                                                 \
        (unsigned long long)dlo | ((unsigned long long)dhi << 32);                        \
  } while (0)

#define MFMA_TILE(BUF, BS) do {                                                           \
    _Pragma("unroll")                                                                     \
    for (int kh = 0; kh < 2; ++kh) {                                                      \
      s16x8 af0 = *(const s16x8*)((BUF) + aOff[kh][0]);                                   \
      s16x8 af1 = *(const s16x8*)((BUF) + aOff[kh][1]);                                   \
      s16x8 mf0 = pos_mask_frag(af0);                                                     \
      s16x8 mf1 = pos_mask_frag(af1);                                                     \
      __builtin_amdgcn_s_setprio(1);                                                      \
      acc1[0][0] = MFMA_(af0, BS[kh * 2 + 0], acc1[0][0], 0, 0, 0);                       \
      acc2[0][0] = MFMA_(mf0, BS[kh * 2 + 0], acc2[0][0], 0, 0, 0);                       \
      acc1[0][1] = MFMA_(af0, BS[kh * 2 + 1], acc1[0][1], 0, 0, 0);                       \
      acc2[0][1] = MFMA_(mf0, BS[kh * 2 + 1], acc2[0][1], 0, 0, 0);                       \
      acc1[1][0] = MFMA_(af1, BS[kh * 2 + 0], acc1[1][0], 0, 0, 0);                       \
      acc2[1][0] = MFMA_(mf1, BS[kh * 2 + 0], acc2[1][0], 0, 0, 0);                       \
      acc1[1][1] = MFMA_(af1, BS[kh * 2 + 1], acc1[1][1], 0, 0, 0);                       \
      acc2[1][1] = MFMA_(mf1, BS[kh * 2 + 1], acc2[1][1], 0, 0, 0);                       \
      __builtin_amdgcn_s_setprio(0);                                                      \
    }                                                                                     \
  } while (0)

#define SYNC() do { FENCE(); WAITLGKM(); FENCE(); BARRIER(); FENCE(); } while (0)

  // ---- prologue ----
  ISSUE_A(x, 0);
  LOADB(bX, 0);
  ISSUE_A(y, 1);
  XFORM(x, buf0);                // compiler waits x precisely, leaves bX/y in flight
  SYNC();

  // ---- steady: tiles 0..125, unrolled by 2 ----
  for (int kt = 0; kt < 126; kt += 2) {
    ISSUE_A(x, kt + 2);
    LOADB(bY, kt + 1);
    FENCE();                     // pin load issue above the MFMA cluster
    MFMA_TILE(buf0, bX);
    XFORM(y, buf1);
    SYNC();
    ISSUE_A(y, kt + 3);
    LOADB(bX, kt + 2);
    FENCE();
    MFMA_TILE(buf1, bY);
    XFORM(x, buf0);
    SYNC();
  }

  // ---- tail: tiles 126, 127 ----
  LOADB(bY, 127);
  FENCE();
  MFMA_TILE(buf0, bX);
  XFORM(y, buf1);                // A(127)
  SYNC();
  MFMA_TILE(buf1, bY);

  // ---- stats: reduce over sp (16 consecutive lanes share row sm) ----
#pragma unroll
  for (int o = 1; o < 16; o <<= 1) {
    s1 += __shfl_xor(s1, o);
    cnt += __shfl_xor(cnt, o);
  }
  __syncthreads();               // everyone past buf0 reads -> reuse as stats
  float* const invsS = (float*)buf0;    // 32 floats
  float* const rdegS = invsS + 32;      // 32 floats
  if (sp == 0) {
    double sq = sqrt((double)cnt);
    invsS[sm] = (cnt > 0) ? (float)(1.0 / sq) : 0.0f;
    rdegS[sm] = (float)(1.0 / (s1 + sq));
  }
  __syncthreads();

  // ---- epilogue: (acc1 + invs*acc2) * rdeg ----
#pragma unroll
  for (int rg = 0; rg < 2; ++rg) {
#pragma unroll
    for (int cg = 0; cg < 2; ++cg) {
#pragma unroll
      for (int j = 0; j < 4; ++j) {
        int row = rg * 16 + q * 4 + j;
        out[(size_t)(brow + row) * DDIM + nt * 256 + wv * 32 + cg * 16 + r] =
            (acc1[rg][cg][j] + invsS[row] * acc2[rg][cg][j]) * rdegS[row];
      }
    }
  }
#undef ISSUE_A
#undef LOADB
#undef XFORM
#undef MFMA_TILE
#undef SYNC
}

extern "C" void kernel_launch(void* const* d_in, const int* in_sizes, int n_in,
                              void* d_out, int out_size, void* d_ws, size_t ws_size,
                              hipStream_t stream) {
  const float* cur = (const float*)d_in[0];          // [8192, 512] fp32
  const float* incm = (const float*)d_in[1];         // [8192, 8192] fp32
  float* out = (float*)d_out;                        // [8192, 512] fp32
  unsigned char* bws = (unsigned char*)d_ws;         // 8MB B chunks

  hipLaunchKernelGGL(bprep_kernel, dim3((NROWS * DDIM / 8) / 256), dim3(256), 0, stream,
                     cur, bws);
  hipLaunchKernelGGL(gemm_kernel, dim3(512), dim3(512), 0, stream, incm, bws, out);
}